// Round 5
// baseline (619.446 us; speedup 1.0000x reference)
//
#include <hip/hip_runtime.h>

// Differentiable SVM (multiclass hinge, 15 GD steps) on MI355X — Round 5.
// bf16 MFMA, fragment-packed operands. Redundant-traffic reduction:
//   k_packS:       ONE kernel writes both SpackA and SpackB (S read once).
//   k_scores_grad: 256 blk x 512 thr; A-tile LDS-staged; wave = jt column.
//   k_update:      256 blk x 256 thr; block = (kt2, jhalf) stages SpackB
//                  column in LDS (2 x 64 KB halves); wave = full-K W tile;
//                  fused W update + re-pack + bias. XCD-swizzled blockIdx.
//   k_query:       direct fp32 Q read + inline bf16 convert (no Q pack).
//
// Fragment layout (v_mfma_f32_16x16x32_bf16), lane l, g=l>>4, q=l&15:
//   A: A[row=q][k=8g+e]  B: B[col=q][k=8g+e]  D: D[row=4g+r][col=q]
// Pack layouts ([tile][lane][8] ushort, 1KB tiles):
//   SpackA: tile(rt,kt):  ((rt*64+kt)*64  + 16*((k&31)>>3)+(r&15))*8+(k&7)
//   SpackB: tile(kt2,it): ((kt2*128+it)*64 + 16*((i&31)>>3)+(k&15))*8+(i&7)
//   WTpack: tile(kt,jt):  ((kt*8+jt)*64   + 16*((k&31)>>3)+(j&15))*8+(k&7)
//   Gpack:  tile(jt,it):  ((jt*128+it)*64 + 16*((i&31)>>3)+(j&15))*8+(i&7)

#define NS 4096
#define DIM 2048
#define NQ 16384
#define NC 128
#define LRATE 0.01f
#define SHRINK (1.0f - 0.01f * 1.0f)
#define GINVF (1.0f / (4096.0f * 128.0f))   // 2^-19, exact in bf16
#define MAX_ITER 15

typedef __attribute__((ext_vector_type(8))) short short8v;
typedef __attribute__((ext_vector_type(8))) unsigned short ushort8v;
typedef __attribute__((ext_vector_type(4))) float f32x4;

__device__ __forceinline__ unsigned short f2bf(float f) {     // RNE
    unsigned int u = __float_as_uint(f);
    u += 0x7fffu + ((u >> 16) & 1u);
    return (unsigned short)(u >> 16);
}
__device__ __forceinline__ float bf2f(unsigned short h) {
    return __uint_as_float(((unsigned int)h) << 16);
}
#define MFMA16(a, b, c) __builtin_amdgcn_mfma_f32_16x16x32_bf16((a), (b), (c), 0, 0, 0)

// ---------------------------------------------------------------------------
// Fused S pack: one read of S -> SpackA (A layout) + SpackB (B layout).
// Grid (16 k-regions, 128 row-regions) x 256 thr.
// ---------------------------------------------------------------------------
__global__ __launch_bounds__(256) void k_packS(const float* __restrict__ src,
                                               unsigned short* __restrict__ dstA,
                                               unsigned short* __restrict__ dstB)
{
    __shared__ float sA[32][132];
    const int tid = threadIdx.x;
    const int i0 = blockIdx.y * 32;
    const int k0 = blockIdx.x * 128;

    #pragma unroll
    for (int u = 0; u < 4; ++u) {
        const int f = tid + 256 * u;
        const int row = f >> 5, c4 = (f & 31) << 2;
        *reinterpret_cast<float4*>(&sA[row][c4]) =
            *reinterpret_cast<const float4*>(&src[(size_t)(i0 + row) * DIM + k0 + c4]);
    }
    __syncthreads();

    #pragma unroll
    for (int u = 0; u < 2; ++u) {           // A-layout writes
        const int s = tid + 256 * u;
        const int lane = s & 63, g = lane >> 4, q = lane & 15;
        const int rtl = s >> 8, ktl = (s >> 6) & 3;
        ushort8v v;
        const float* p = &sA[16 * rtl + q][32 * ktl + 8 * g];
        #pragma unroll
        for (int e = 0; e < 8; ++e) v[e] = f2bf(p[e]);
        const size_t rt_g = blockIdx.y * 2 + rtl;
        const size_t kt_g = blockIdx.x * 4 + ktl;
        *reinterpret_cast<ushort8v*>(&dstA[((rt_g * 64 + kt_g) * 64 + lane) * 8]) = v;
    }
    #pragma unroll
    for (int u = 0; u < 2; ++u) {           // B-layout writes
        const int s = tid + 256 * u;
        const int lane = s & 63, g = lane >> 4, q = lane & 15;
        const int kt2l = s >> 6;            // 0..7
        ushort8v v;
        #pragma unroll
        for (int e = 0; e < 8; ++e) v[e] = f2bf(sA[8 * g + e][16 * kt2l + q]);
        const size_t kt2_g = blockIdx.x * 8 + kt2l;
        *reinterpret_cast<ushort8v*>(
            &dstB[((kt2_g * 128 + blockIdx.y) * 64 + lane) * 8]) = v;
    }
}

// ---------------------------------------------------------------------------
// K1: scores + hinge grad -> Gpack. 256 blocks x 512 thr (8 waves).
// Block owns rt (16 rows); A-tile (64 KB) staged to LDS once; wave w = jt.
// ---------------------------------------------------------------------------
__global__ __launch_bounds__(512) void k_scores_grad(
    const unsigned short* __restrict__ SpackA,
    const unsigned short* __restrict__ WTpack,
    const float* __restrict__ bias,
    const int* __restrict__ labels,
    unsigned short* __restrict__ Gpack)
{
    __shared__ unsigned short sQ[32768];   // 64 KB A-tile, fragment order
    __shared__ float sS[16][132];
    __shared__ int   sLab[16];
    __shared__ float sScorr[16];
    __shared__ int   sCnt[16];

    const int tid = threadIdx.x;
    const int w = tid >> 6, lane = tid & 63;
    const int g = lane >> 4, q = lane & 15;
    const int rt = blockIdx.x;
    const int ibase = rt * 16;

    if (tid < 16) sLab[tid] = labels[ibase + tid];

    {   // stage A tile: linear 64 KB copy
        const unsigned short* src = SpackA + (size_t)rt * 32768;
        #pragma unroll
        for (int u = 0; u < 8; ++u) {
            const int o = (tid + 512 * u) * 8;
            *reinterpret_cast<ushort8v*>(&sQ[o]) =
                *reinterpret_cast<const ushort8v*>(&src[o]);
        }
    }
    __syncthreads();

    const int jt = w;
    f32x4 acc = {};
    const unsigned short* bp = WTpack + (size_t)jt * 512 + lane * 8;
    #pragma unroll 4
    for (int kt = 0; kt < 64; ++kt) {
        const short8v a = *reinterpret_cast<const short8v*>(&sQ[(kt * 64 + lane) * 8]);
        const short8v b = *reinterpret_cast<const short8v*>(bp + (size_t)kt * 4096);
        acc = MFMA16(a, b, acc);
    }

    const float bq = bias[jt * 16 + q];
    #pragma unroll
    for (int r = 0; r < 4; ++r)
        sS[4 * g + r][jt * 16 + q] = acc[r] + bq;
    __syncthreads();

    if (tid < 256) {   // per-row correct score + indicator count
        const int row = tid >> 4;
        const int c0 = (tid & 15) * 8;
        const int lab = sLab[row];
        const float scorr = sS[row][lab];
        int cnt = 0;
        #pragma unroll
        for (int c = 0; c < 8; ++c) {
            const int col = c0 + c;
            cnt += (col != lab && (sS[row][col] - scorr + 1.0f > 0.0f)) ? 1 : 0;
        }
        cnt += __shfl_xor(cnt, 1); cnt += __shfl_xor(cnt, 2);
        cnt += __shfl_xor(cnt, 4); cnt += __shfl_xor(cnt, 8);
        if ((tid & 15) == 0) { sCnt[row] = cnt; sScorr[row] = scorr; }
    }
    __syncthreads();

    if (tid < 256) {   // write Gpack, one ushort8 (8 rows x 1 class) per thread
        const int j = tid & 127, h = tid >> 7;
        const int jt2 = j >> 4, qq = j & 15;
        const int it = rt >> 1, g2 = ((rt & 1) << 1) + h;
        const unsigned short BF_GINV = f2bf(GINVF);
        ushort8v gv;
        #pragma unroll
        for (int e = 0; e < 8; ++e) {
            const int row = 8 * h + e;
            const int lab = sLab[row];
            unsigned short v;
            if (j == lab) v = f2bf(-(float)sCnt[row] * GINVF);
            else v = (sS[row][j] - sScorr[row] + 1.0f > 0.0f) ? BF_GINV : (unsigned short)0;
            gv[e] = v;
        }
        *reinterpret_cast<ushort8v*>(
            &Gpack[((size_t)(jt2 * 128 + it) * 64 + g2 * 16 + qq) * 8]) = gv;
    }
}

// ---------------------------------------------------------------------------
// K2: fused dW GEMM + W update + re-pack + bias grad.
// Grid 256 blk x 256 thr (4 waves). Block = (kt2, jhalf): stages SpackB
// column in LDS (two 64 KB halves); wave w -> jt = jhalf*4+w owns the full-K
// (jt,kt2) 16x16 W tile. bid swizzle co-locates jhalf mates on one XCD.
// ---------------------------------------------------------------------------
__global__ __launch_bounds__(256) void k_update(
    const unsigned short* __restrict__ Gpack,
    const unsigned short* __restrict__ SpackB,
    float* __restrict__ WT, float* __restrict__ biasp,
    unsigned short* __restrict__ WTpack)
{
    __shared__ unsigned short sB[32768];   // 64 KB: 64 it-tiles of this kt2

    const int bid = blockIdx.x;            // swizzle: mates (kt2,0/1) 8 apart
    const int jhalf = (bid >> 3) & 1;
    const int kt2 = (bid & 7) | ((bid >> 4) << 3);
    const int tid = threadIdx.x, w = tid >> 6, lane = tid & 63;
    const int g = lane >> 4, q = lane & 15;
    const int jt = jhalf * 4 + w;
    const bool bias_tile = (kt2 == 0);

    f32x4 acc = {};
    float bsum = 0.0f;
    const unsigned short* ga = Gpack + (size_t)jt * 128 * 512 + lane * 8;

    for (int half = 0; half < 2; ++half) {
        const unsigned short* src = SpackB + ((size_t)kt2 * 128 + half * 64) * 512;
        __syncthreads();
        #pragma unroll
        for (int u = 0; u < 16; ++u) {
            const int o = (tid + 256 * u) * 8;
            *reinterpret_cast<ushort8v*>(&sB[o]) =
                *reinterpret_cast<const ushort8v*>(&src[o]);
        }
        __syncthreads();
        const unsigned short* gah = ga + (size_t)half * 64 * 512;
        if (bias_tile) {
            #pragma unroll 8
            for (int it = 0; it < 64; ++it) {
                const short8v a = *reinterpret_cast<const short8v*>(gah + (size_t)it * 512);
                const short8v b = *reinterpret_cast<const short8v*>(&sB[(it * 64 + lane) * 8]);
                acc = MFMA16(a, b, acc);
                #pragma unroll
                for (int e = 0; e < 8; ++e) bsum += bf2f((unsigned short)a[e]);
            }
        } else {
            #pragma unroll 8
            for (int it = 0; it < 64; ++it) {
                const short8v a = *reinterpret_cast<const short8v*>(gah + (size_t)it * 512);
                const short8v b = *reinterpret_cast<const short8v*>(&sB[(it * 64 + lane) * 8]);
                acc = MFMA16(a, b, acc);
            }
        }
    }

    #pragma unroll
    for (int r = 0; r < 4; ++r) {
        const int j = jt * 16 + 4 * g + r;
        const int k = kt2 * 16 + q;
        float wv = WT[(size_t)j * DIM + k];
        wv = wv * SHRINK - LRATE * acc[r];
        WT[(size_t)j * DIM + k] = wv;
        WTpack[((size_t)((k >> 5) * 8 + jt) * 64
                + ((k & 31) >> 3) * 16 + (j & 15)) * 8 + (k & 7)] = f2bf(wv);
    }

    if (bias_tile) {
        bsum += __shfl_xor(bsum, 16);
        bsum += __shfl_xor(bsum, 32);
        if (lane < 16) biasp[jt * 16 + lane] -= LRATE * bsum;
    }
}

// ---------------------------------------------------------------------------
// K3: out = Q @ WT^T + bias. Direct fp32 Q read + inline bf16 convert.
// 512 blk x 128 thr (1024 waves); wave = 1 row-tile x 8 class-tiles.
// ---------------------------------------------------------------------------
__global__ __launch_bounds__(128) void k_query(
    const float* __restrict__ Qf,
    const unsigned short* __restrict__ WTpack,
    const float* __restrict__ bias,
    float* __restrict__ out)
{
    const int tid = threadIdx.x, w = tid >> 6, lane = tid & 63;
    const int g = lane >> 4, q = lane & 15;
    const int rt = blockIdx.x * 2 + w;

    f32x4 acc[8] = {};
    const float* qrow = Qf + (size_t)(rt * 16 + q) * DIM + 8 * g;
    const unsigned short* bp = WTpack + lane * 8;
    for (int kt = 0; kt < 64; ++kt) {
        const float4 f0 = *reinterpret_cast<const float4*>(qrow + kt * 32);
        const float4 f1 = *reinterpret_cast<const float4*>(qrow + kt * 32 + 4);
        short8v a;
        a[0] = (short)f2bf(f0.x); a[1] = (short)f2bf(f0.y);
        a[2] = (short)f2bf(f0.z); a[3] = (short)f2bf(f0.w);
        a[4] = (short)f2bf(f1.x); a[5] = (short)f2bf(f1.y);
        a[6] = (short)f2bf(f1.z); a[7] = (short)f2bf(f1.w);
        const unsigned short* bb = bp + (size_t)kt * 4096;
        #pragma unroll
        for (int jt = 0; jt < 8; ++jt) {
            const short8v bv = *reinterpret_cast<const short8v*>(bb + jt * 512);
            acc[jt] = MFMA16(a, bv, acc[jt]);
        }
    }
    const int row0 = rt * 16 + 4 * g;
    #pragma unroll
    for (int jt = 0; jt < 8; ++jt) {
        const float bq = bias[jt * 16 + q];
        #pragma unroll
        for (int r = 0; r < 4; ++r)
            out[(size_t)(row0 + r) * NC + jt * 16 + q] = acc[jt][r] + bq;
    }
}

// ---------------------------------------------------------------------------
extern "C" void kernel_launch(void* const* d_in, const int* in_sizes, int n_in,
                              void* d_out, int out_size, void* d_ws, size_t ws_size,
                              hipStream_t stream)
{
    const float* S      = (const float*)d_in[0];
    const int*   labels = (const int*)d_in[1];
    const float* Q      = (const float*)d_in[2];
    float* out = (float*)d_out;

    char* ws = (char*)d_ws;
    float*          WT     = (float*)(ws + 0);                 // 1,048,576
    float*          bias   = (float*)(ws + 1048576);           // 512
    unsigned short* WTpack = (unsigned short*)(ws + 1049088);  // 524,288
    unsigned short* Gpack  = (unsigned short*)(ws + 1573376);  // 1,048,576
    unsigned short* SpackA = (unsigned short*)(ws + 2621952);  // 16 MB
    unsigned short* SpackB = (unsigned short*)(ws + 19399168); // 16 MB
    // total: ~36 MB

    hipMemsetAsync(ws, 0, 1573376, stream);   // WT + bias + WTpack

    k_packS<<<dim3(16, 128), 256, 0, stream>>>(S, SpackA, SpackB);

    for (int it = 0; it < MAX_ITER; ++it) {
        k_scores_grad<<<dim3(256), dim3(512), 0, stream>>>(SpackA, WTpack, bias, labels, Gpack);
        k_update<<<dim3(256), dim3(256), 0, stream>>>(Gpack, SpackB, WT, bias, WTpack);
    }
    k_query<<<dim3(512), dim3(128), 0, stream>>>(Q, WTpack, bias, out);
}

// Round 6
// 596.100 us; speedup vs baseline: 1.0392x; 1.0392x over previous
//
#include <hip/hip_runtime.h>

// Differentiable SVM (multiclass hinge, 15 GD steps) on MI355X — Round 6.
// = Round 5, with k_query rebuilt: coalesced fp32 Q reads -> LDS (row-major
// bf16, XOR-swizzled) -> MFMA fragments. No Q pack, no uncoalesced reads.
//
// Fragment layout (v_mfma_f32_16x16x32_bf16), lane l, g=l>>4, q=l&15:
//   A: A[row=q][k=8g+e]  B: B[col=q][k=8g+e]  D: D[row=4g+r][col=q]
// Pack layouts ([tile][lane][8] ushort, 1KB tiles):
//   SpackA: tile(rt,kt):  ((rt*64+kt)*64  + 16*((k&31)>>3)+(r&15))*8+(k&7)
//   SpackB: tile(kt2,it): ((kt2*128+it)*64 + 16*((i&31)>>3)+(k&15))*8+(i&7)
//   WTpack: tile(kt,jt):  ((kt*8+jt)*64   + 16*((k&31)>>3)+(j&15))*8+(k&7)
//   Gpack:  tile(jt,it):  ((jt*128+it)*64 + 16*((i&31)>>3)+(j&15))*8+(i&7)

#define NS 4096
#define DIM 2048
#define NQ 16384
#define NC 128
#define LRATE 0.01f
#define SHRINK (1.0f - 0.01f * 1.0f)
#define GINVF (1.0f / (4096.0f * 128.0f))   // 2^-19, exact in bf16
#define MAX_ITER 15

typedef __attribute__((ext_vector_type(8))) short short8v;
typedef __attribute__((ext_vector_type(8))) unsigned short ushort8v;
typedef __attribute__((ext_vector_type(4))) unsigned short ushort4v;
typedef __attribute__((ext_vector_type(4))) float f32x4;

__device__ __forceinline__ unsigned short f2bf(float f) {     // RNE
    unsigned int u = __float_as_uint(f);
    u += 0x7fffu + ((u >> 16) & 1u);
    return (unsigned short)(u >> 16);
}
__device__ __forceinline__ float bf2f(unsigned short h) {
    return __uint_as_float(((unsigned int)h) << 16);
}
#define MFMA16(a, b, c) __builtin_amdgcn_mfma_f32_16x16x32_bf16((a), (b), (c), 0, 0, 0)

// ---------------------------------------------------------------------------
// Fused S pack: one read of S -> SpackA (A layout) + SpackB (B layout).
// ---------------------------------------------------------------------------
__global__ __launch_bounds__(256) void k_packS(const float* __restrict__ src,
                                               unsigned short* __restrict__ dstA,
                                               unsigned short* __restrict__ dstB)
{
    __shared__ float sA[32][132];
    const int tid = threadIdx.x;
    const int i0 = blockIdx.y * 32;
    const int k0 = blockIdx.x * 128;

    #pragma unroll
    for (int u = 0; u < 4; ++u) {
        const int f = tid + 256 * u;
        const int row = f >> 5, c4 = (f & 31) << 2;
        *reinterpret_cast<float4*>(&sA[row][c4]) =
            *reinterpret_cast<const float4*>(&src[(size_t)(i0 + row) * DIM + k0 + c4]);
    }
    __syncthreads();

    #pragma unroll
    for (int u = 0; u < 2; ++u) {           // A-layout writes
        const int s = tid + 256 * u;
        const int lane = s & 63, g = lane >> 4, q = lane & 15;
        const int rtl = s >> 8, ktl = (s >> 6) & 3;
        ushort8v v;
        const float* p = &sA[16 * rtl + q][32 * ktl + 8 * g];
        #pragma unroll
        for (int e = 0; e < 8; ++e) v[e] = f2bf(p[e]);
        const size_t rt_g = blockIdx.y * 2 + rtl;
        const size_t kt_g = blockIdx.x * 4 + ktl;
        *reinterpret_cast<ushort8v*>(&dstA[((rt_g * 64 + kt_g) * 64 + lane) * 8]) = v;
    }
    #pragma unroll
    for (int u = 0; u < 2; ++u) {           // B-layout writes
        const int s = tid + 256 * u;
        const int lane = s & 63, g = lane >> 4, q = lane & 15;
        const int kt2l = s >> 6;            // 0..7
        ushort8v v;
        #pragma unroll
        for (int e = 0; e < 8; ++e) v[e] = f2bf(sA[8 * g + e][16 * kt2l + q]);
        const size_t kt2_g = blockIdx.x * 8 + kt2l;
        *reinterpret_cast<ushort8v*>(
            &dstB[((kt2_g * 128 + blockIdx.y) * 64 + lane) * 8]) = v;
    }
}

// ---------------------------------------------------------------------------
// K1: scores + hinge grad -> Gpack. 256 blocks x 512 thr (8 waves).
// ---------------------------------------------------------------------------
__global__ __launch_bounds__(512) void k_scores_grad(
    const unsigned short* __restrict__ SpackA,
    const unsigned short* __restrict__ WTpack,
    const float* __restrict__ bias,
    const int* __restrict__ labels,
    unsigned short* __restrict__ Gpack)
{
    __shared__ unsigned short sQ[32768];   // 64 KB A-tile, fragment order
    __shared__ float sS[16][132];
    __shared__ int   sLab[16];
    __shared__ float sScorr[16];
    __shared__ int   sCnt[16];

    const int tid = threadIdx.x;
    const int w = tid >> 6, lane = tid & 63;
    const int g = lane >> 4, q = lane & 15;
    const int rt = blockIdx.x;
    const int ibase = rt * 16;

    if (tid < 16) sLab[tid] = labels[ibase + tid];

    {   // stage A tile: linear 64 KB copy
        const unsigned short* src = SpackA + (size_t)rt * 32768;
        #pragma unroll
        for (int u = 0; u < 8; ++u) {
            const int o = (tid + 512 * u) * 8;
            *reinterpret_cast<ushort8v*>(&sQ[o]) =
                *reinterpret_cast<const ushort8v*>(&src[o]);
        }
    }
    __syncthreads();

    const int jt = w;
    f32x4 acc = {};
    const unsigned short* bp = WTpack + (size_t)jt * 512 + lane * 8;
    #pragma unroll 4
    for (int kt = 0; kt < 64; ++kt) {
        const short8v a = *reinterpret_cast<const short8v*>(&sQ[(kt * 64 + lane) * 8]);
        const short8v b = *reinterpret_cast<const short8v*>(bp + (size_t)kt * 4096);
        acc = MFMA16(a, b, acc);
    }

    const float bq = bias[jt * 16 + q];
    #pragma unroll
    for (int r = 0; r < 4; ++r)
        sS[4 * g + r][jt * 16 + q] = acc[r] + bq;
    __syncthreads();

    if (tid < 256) {   // per-row correct score + indicator count
        const int row = tid >> 4;
        const int c0 = (tid & 15) * 8;
        const int lab = sLab[row];
        const float scorr = sS[row][lab];
        int cnt = 0;
        #pragma unroll
        for (int c = 0; c < 8; ++c) {
            const int col = c0 + c;
            cnt += (col != lab && (sS[row][col] - scorr + 1.0f > 0.0f)) ? 1 : 0;
        }
        cnt += __shfl_xor(cnt, 1); cnt += __shfl_xor(cnt, 2);
        cnt += __shfl_xor(cnt, 4); cnt += __shfl_xor(cnt, 8);
        if ((tid & 15) == 0) { sCnt[row] = cnt; sScorr[row] = scorr; }
    }
    __syncthreads();

    if (tid < 256) {   // write Gpack, one ushort8 (8 rows x 1 class) per thread
        const int j = tid & 127, h = tid >> 7;
        const int jt2 = j >> 4, qq = j & 15;
        const int it = rt >> 1, g2 = ((rt & 1) << 1) + h;
        const unsigned short BF_GINV = f2bf(GINVF);
        ushort8v gv;
        #pragma unroll
        for (int e = 0; e < 8; ++e) {
            const int row = 8 * h + e;
            const int lab = sLab[row];
            unsigned short v;
            if (j == lab) v = f2bf(-(float)sCnt[row] * GINVF);
            else v = (sS[row][j] - sScorr[row] + 1.0f > 0.0f) ? BF_GINV : (unsigned short)0;
            gv[e] = v;
        }
        *reinterpret_cast<ushort8v*>(
            &Gpack[((size_t)(jt2 * 128 + it) * 64 + g2 * 16 + qq) * 8]) = gv;
    }
}

// ---------------------------------------------------------------------------
// K2: fused dW GEMM + W update + re-pack + bias grad. 256 blk x 256 thr.
// ---------------------------------------------------------------------------
__global__ __launch_bounds__(256) void k_update(
    const unsigned short* __restrict__ Gpack,
    const unsigned short* __restrict__ SpackB,
    float* __restrict__ WT, float* __restrict__ biasp,
    unsigned short* __restrict__ WTpack)
{
    __shared__ unsigned short sB[32768];   // 64 KB: 64 it-tiles of this kt2

    const int bid = blockIdx.x;            // swizzle: mates (kt2,0/1) 8 apart
    const int jhalf = (bid >> 3) & 1;
    const int kt2 = (bid & 7) | ((bid >> 4) << 3);
    const int tid = threadIdx.x, w = tid >> 6, lane = tid & 63;
    const int g = lane >> 4, q = lane & 15;
    const int jt = jhalf * 4 + w;
    const bool bias_tile = (kt2 == 0);

    f32x4 acc = {};
    float bsum = 0.0f;
    const unsigned short* ga = Gpack + (size_t)jt * 128 * 512 + lane * 8;

    for (int half = 0; half < 2; ++half) {
        const unsigned short* src = SpackB + ((size_t)kt2 * 128 + half * 64) * 512;
        __syncthreads();
        #pragma unroll
        for (int u = 0; u < 16; ++u) {
            const int o = (tid + 256 * u) * 8;
            *reinterpret_cast<ushort8v*>(&sB[o]) =
                *reinterpret_cast<const ushort8v*>(&src[o]);
        }
        __syncthreads();
        const unsigned short* gah = ga + (size_t)half * 64 * 512;
        if (bias_tile) {
            #pragma unroll 8
            for (int it = 0; it < 64; ++it) {
                const short8v a = *reinterpret_cast<const short8v*>(gah + (size_t)it * 512);
                const short8v b = *reinterpret_cast<const short8v*>(&sB[(it * 64 + lane) * 8]);
                acc = MFMA16(a, b, acc);
                #pragma unroll
                for (int e = 0; e < 8; ++e) bsum += bf2f((unsigned short)a[e]);
            }
        } else {
            #pragma unroll 8
            for (int it = 0; it < 64; ++it) {
                const short8v a = *reinterpret_cast<const short8v*>(gah + (size_t)it * 512);
                const short8v b = *reinterpret_cast<const short8v*>(&sB[(it * 64 + lane) * 8]);
                acc = MFMA16(a, b, acc);
            }
        }
    }

    #pragma unroll
    for (int r = 0; r < 4; ++r) {
        const int j = jt * 16 + 4 * g + r;
        const int k = kt2 * 16 + q;
        float wv = WT[(size_t)j * DIM + k];
        wv = wv * SHRINK - LRATE * acc[r];
        WT[(size_t)j * DIM + k] = wv;
        WTpack[((size_t)((k >> 5) * 8 + jt) * 64
                + ((k & 31) >> 3) * 16 + (j & 15)) * 8 + (k & 7)] = f2bf(wv);
    }

    if (bias_tile) {
        bsum += __shfl_xor(bsum, 16);
        bsum += __shfl_xor(bsum, 32);
        if (lane < 16) biasp[jt * 16 + lane] -= LRATE * bsum;
    }
}

// ---------------------------------------------------------------------------
// K3: out = Q @ WT^T + bias. 256 blk x 256 thr (4 waves); block = 64 rows.
// Coalesced fp32 reads -> regs -> LDS row-major bf16 (XOR swizzle) -> frags.
// Chunked K (128 floats/chunk), register prefetch of chunk c+1 under MFMA.
// ---------------------------------------------------------------------------
__global__ __launch_bounds__(256) void k_query(
    const float* __restrict__ Qf,
    const unsigned short* __restrict__ WTpack,
    const float* __restrict__ bias,
    float* __restrict__ out)
{
    __shared__ __align__(16) unsigned char sQb[16384];  // [64 rows][128 k] bf16

    const int tid = threadIdx.x, w = tid >> 6, lane = tid & 63;
    const int g = lane >> 4, q = lane & 15;
    const int row0 = blockIdx.x * 64;
    const float* qbase = Qf + (size_t)row0 * DIM;

    f32x4 acc[8] = {};
    float4 regs[8];

    // prologue: load chunk 0 (coalesced: 32 consecutive lanes span one row)
    #pragma unroll
    for (int u = 0; u < 8; ++u) {
        const int s = tid + 256 * u;
        regs[u] = *reinterpret_cast<const float4*>(
            &qbase[(size_t)(s >> 5) * DIM + ((s & 31) << 2)]);
    }

    for (int c = 0; c < 16; ++c) {
        // regs -> LDS row-major bf16, swizzled; 8B writes, conflict-free
        #pragma unroll
        for (int u = 0; u < 8; ++u) {
            const int s = tid + 256 * u;
            const int row = s >> 5, c4 = (s & 31) << 2;
            const int byte = (row * 256 + c4 * 2) ^ ((row & 7) << 4);
            ushort4v v;
            v[0] = f2bf(regs[u].x); v[1] = f2bf(regs[u].y);
            v[2] = f2bf(regs[u].z); v[3] = f2bf(regs[u].w);
            *reinterpret_cast<ushort4v*>(&sQb[byte]) = v;
        }
        __syncthreads();

        // issue next chunk's loads (latency hides under MFMA below)
        if (c < 15) {
            #pragma unroll
            for (int u = 0; u < 8; ++u) {
                const int s = tid + 256 * u;
                regs[u] = *reinterpret_cast<const float4*>(
                    &qbase[(size_t)(s >> 5) * DIM + (c + 1) * 128 + ((s & 31) << 2)]);
            }
        }

        // compute: wave w owns rows w*16..w*16+15
        const int row = w * 16 + q;
        const int rbase = row * 256;
        const int swz = (q & 7) << 4;
        #pragma unroll
        for (int kt_l = 0; kt_l < 4; ++kt_l) {
            const short8v a = *reinterpret_cast<const short8v*>(
                &sQb[(rbase + kt_l * 64 + g * 16) ^ swz]);
            const int kt = c * 4 + kt_l;
            const unsigned short* bb = WTpack + (size_t)kt * 4096 + lane * 8;
            #pragma unroll
            for (int jt = 0; jt < 8; ++jt) {
                const short8v bv = *reinterpret_cast<const short8v*>(bb + jt * 512);
                acc[jt] = MFMA16(a, bv, acc[jt]);
            }
        }
        __syncthreads();
    }

    const int orow0 = row0 + w * 16 + 4 * g;
    #pragma unroll
    for (int jt = 0; jt < 8; ++jt) {
        const float bq = bias[jt * 16 + q];
        #pragma unroll
        for (int r = 0; r < 4; ++r)
            out[(size_t)(orow0 + r) * NC + jt * 16 + q] = acc[jt][r] + bq;
    }
}

// ---------------------------------------------------------------------------
extern "C" void kernel_launch(void* const* d_in, const int* in_sizes, int n_in,
                              void* d_out, int out_size, void* d_ws, size_t ws_size,
                              hipStream_t stream)
{
    const float* S      = (const float*)d_in[0];
    const int*   labels = (const int*)d_in[1];
    const float* Q      = (const float*)d_in[2];
    float* out = (float*)d_out;

    char* ws = (char*)d_ws;
    float*          WT     = (float*)(ws + 0);                 // 1,048,576
    float*          bias   = (float*)(ws + 1048576);           // 512
    unsigned short* WTpack = (unsigned short*)(ws + 1049088);  // 524,288
    unsigned short* Gpack  = (unsigned short*)(ws + 1573376);  // 1,048,576
    unsigned short* SpackA = (unsigned short*)(ws + 2621952);  // 16 MB
    unsigned short* SpackB = (unsigned short*)(ws + 19399168); // 16 MB
    // total: ~36 MB

    hipMemsetAsync(ws, 0, 1573376, stream);   // WT + bias + WTpack

    k_packS<<<dim3(16, 128), 256, 0, stream>>>(S, SpackA, SpackB);

    for (int it = 0; it < MAX_ITER; ++it) {
        k_scores_grad<<<dim3(256), dim3(512), 0, stream>>>(SpackA, WTpack, bias, labels, Gpack);
        k_update<<<dim3(256), dim3(256), 0, stream>>>(Gpack, SpackB, WT, bias, WTpack);
    }
    k_query<<<dim3(256), dim3(256), 0, stream>>>(Q, WTpack, bias, out);
}

// Round 7
// 420.045 us; speedup vs baseline: 1.4747x; 1.4191x over previous
//
#include <hip/hip_runtime.h>

// Differentiable SVM (multiclass hinge, 15 GD steps) on MI355X — Round 7.
// Changes vs R6:
//   k_query: chunk-staged BOTH operands in LDS (Q 16KB swizzled + WT 32KB
//            linear), double-buffered, 1 barrier/chunk, issue-early loads.
//   k_scores_grad / k_update: 8-deep ping-pong register prefetch of the
//            global fragment stream (WTpack / Gpack) to hide L2/L3 latency.
//
// Fragment layout (v_mfma_f32_16x16x32_bf16), lane l, g=l>>4, q=l&15:
//   A: A[row=q][k=8g+e]  B: B[col=q][k=8g+e]  D: D[row=4g+r][col=q]
// Pack layouts ([tile][lane][8] ushort, 1KB tiles):
//   SpackA: tile(rt,kt):  ((rt*64+kt)*64  + 16*((k&31)>>3)+(r&15))*8+(k&7)
//   SpackB: tile(kt2,it): ((kt2*128+it)*64 + 16*((i&31)>>3)+(k&15))*8+(i&7)
//   WTpack: tile(kt,jt):  ((kt*8+jt)*64   + 16*((k&31)>>3)+(j&15))*8+(k&7)
//   Gpack:  tile(jt,it):  ((jt*128+it)*64 + 16*((i&31)>>3)+(j&15))*8+(i&7)

#define NS 4096
#define DIM 2048
#define NQ 16384
#define NC 128
#define LRATE 0.01f
#define SHRINK (1.0f - 0.01f * 1.0f)
#define GINVF (1.0f / (4096.0f * 128.0f))   // 2^-19, exact in bf16
#define MAX_ITER 15

typedef __attribute__((ext_vector_type(8))) short short8v;
typedef __attribute__((ext_vector_type(8))) unsigned short ushort8v;
typedef __attribute__((ext_vector_type(4))) unsigned short ushort4v;
typedef __attribute__((ext_vector_type(4))) float f32x4;

__device__ __forceinline__ unsigned short f2bf(float f) {     // RNE
    unsigned int u = __float_as_uint(f);
    u += 0x7fffu + ((u >> 16) & 1u);
    return (unsigned short)(u >> 16);
}
__device__ __forceinline__ float bf2f(unsigned short h) {
    return __uint_as_float(((unsigned int)h) << 16);
}
#define MFMA16(a, b, c) __builtin_amdgcn_mfma_f32_16x16x32_bf16((a), (b), (c), 0, 0, 0)

// ---------------------------------------------------------------------------
// Fused S pack: one read of S -> SpackA (A layout) + SpackB (B layout).
// ---------------------------------------------------------------------------
__global__ __launch_bounds__(256) void k_packS(const float* __restrict__ src,
                                               unsigned short* __restrict__ dstA,
                                               unsigned short* __restrict__ dstB)
{
    __shared__ float sA[32][132];
    const int tid = threadIdx.x;
    const int i0 = blockIdx.y * 32;
    const int k0 = blockIdx.x * 128;

    #pragma unroll
    for (int u = 0; u < 4; ++u) {
        const int f = tid + 256 * u;
        const int row = f >> 5, c4 = (f & 31) << 2;
        *reinterpret_cast<float4*>(&sA[row][c4]) =
            *reinterpret_cast<const float4*>(&src[(size_t)(i0 + row) * DIM + k0 + c4]);
    }
    __syncthreads();

    #pragma unroll
    for (int u = 0; u < 2; ++u) {           // A-layout writes
        const int s = tid + 256 * u;
        const int lane = s & 63, g = lane >> 4, q = lane & 15;
        const int rtl = s >> 8, ktl = (s >> 6) & 3;
        ushort8v v;
        const float* p = &sA[16 * rtl + q][32 * ktl + 8 * g];
        #pragma unroll
        for (int e = 0; e < 8; ++e) v[e] = f2bf(p[e]);
        const size_t rt_g = blockIdx.y * 2 + rtl;
        const size_t kt_g = blockIdx.x * 4 + ktl;
        *reinterpret_cast<ushort8v*>(&dstA[((rt_g * 64 + kt_g) * 64 + lane) * 8]) = v;
    }
    #pragma unroll
    for (int u = 0; u < 2; ++u) {           // B-layout writes
        const int s = tid + 256 * u;
        const int lane = s & 63, g = lane >> 4, q = lane & 15;
        const int kt2l = s >> 6;            // 0..7
        ushort8v v;
        #pragma unroll
        for (int e = 0; e < 8; ++e) v[e] = f2bf(sA[8 * g + e][16 * kt2l + q]);
        const size_t kt2_g = blockIdx.x * 8 + kt2l;
        *reinterpret_cast<ushort8v*>(
            &dstB[((kt2_g * 128 + blockIdx.y) * 64 + lane) * 8]) = v;
    }
}

// ---------------------------------------------------------------------------
// K1: scores + hinge grad -> Gpack. 256 blocks x 512 thr (8 waves).
// Block owns rt (16 rows), A-tile LDS; wave = jt; 8-deep b-prefetch ping-pong.
// ---------------------------------------------------------------------------
__global__ __launch_bounds__(512) void k_scores_grad(
    const unsigned short* __restrict__ SpackA,
    const unsigned short* __restrict__ WTpack,
    const float* __restrict__ bias,
    const int* __restrict__ labels,
    unsigned short* __restrict__ Gpack)
{
    __shared__ unsigned short sQ[32768];   // 64 KB A-tile, fragment order
    __shared__ float sS[16][132];
    __shared__ int   sLab[16];
    __shared__ float sScorr[16];
    __shared__ int   sCnt[16];

    const int tid = threadIdx.x;
    const int w = tid >> 6, lane = tid & 63;
    const int g = lane >> 4, q = lane & 15;
    const int rt = blockIdx.x;
    const int ibase = rt * 16;

    if (tid < 16) sLab[tid] = labels[ibase + tid];

    {   // stage A tile: linear 64 KB copy
        const unsigned short* src = SpackA + (size_t)rt * 32768;
        #pragma unroll
        for (int u = 0; u < 8; ++u) {
            const int o = (tid + 512 * u) * 8;
            *reinterpret_cast<ushort8v*>(&sQ[o]) =
                *reinterpret_cast<const ushort8v*>(&src[o]);
        }
    }
    __syncthreads();

    const int jt = w;
    const unsigned short* bp = WTpack + (size_t)jt * 512 + lane * 8;
    short8v b0[8], b1[8];
    #pragma unroll
    for (int e = 0; e < 8; ++e)
        b0[e] = *reinterpret_cast<const short8v*>(bp + (size_t)e * 4096);

    f32x4 acc = {};
    #pragma unroll
    for (int grp = 0; grp < 8; grp += 2) {
        #pragma unroll
        for (int e = 0; e < 8; ++e)
            b1[e] = *reinterpret_cast<const short8v*>(bp + (size_t)((grp + 1) * 8 + e) * 4096);
        #pragma unroll
        for (int e = 0; e < 8; ++e) {
            const short8v a = *reinterpret_cast<const short8v*>(
                &sQ[((grp * 8 + e) * 64 + lane) * 8]);
            acc = MFMA16(a, b0[e], acc);
        }
        if (grp + 2 < 8) {
            #pragma unroll
            for (int e = 0; e < 8; ++e)
                b0[e] = *reinterpret_cast<const short8v*>(bp + (size_t)((grp + 2) * 8 + e) * 4096);
        }
        #pragma unroll
        for (int e = 0; e < 8; ++e) {
            const short8v a = *reinterpret_cast<const short8v*>(
                &sQ[(((grp + 1) * 8 + e) * 64 + lane) * 8]);
            acc = MFMA16(a, b1[e], acc);
        }
    }

    const float bq = bias[jt * 16 + q];
    #pragma unroll
    for (int r = 0; r < 4; ++r)
        sS[4 * g + r][jt * 16 + q] = acc[r] + bq;
    __syncthreads();

    if (tid < 256) {   // per-row correct score + indicator count
        const int row = tid >> 4;
        const int c0 = (tid & 15) * 8;
        const int lab = sLab[row];
        const float scorr = sS[row][lab];
        int cnt = 0;
        #pragma unroll
        for (int c = 0; c < 8; ++c) {
            const int col = c0 + c;
            cnt += (col != lab && (sS[row][col] - scorr + 1.0f > 0.0f)) ? 1 : 0;
        }
        cnt += __shfl_xor(cnt, 1); cnt += __shfl_xor(cnt, 2);
        cnt += __shfl_xor(cnt, 4); cnt += __shfl_xor(cnt, 8);
        if ((tid & 15) == 0) { sCnt[row] = cnt; sScorr[row] = scorr; }
    }
    __syncthreads();

    if (tid < 256) {   // write Gpack, one ushort8 (8 rows x 1 class) per thread
        const int j = tid & 127, h = tid >> 7;
        const int jt2 = j >> 4, qq = j & 15;
        const int it = rt >> 1, g2 = ((rt & 1) << 1) + h;
        const unsigned short BF_GINV = f2bf(GINVF);
        ushort8v gv;
        #pragma unroll
        for (int e = 0; e < 8; ++e) {
            const int row = 8 * h + e;
            const int lab = sLab[row];
            unsigned short v;
            if (j == lab) v = f2bf(-(float)sCnt[row] * GINVF);
            else v = (sS[row][j] - sScorr[row] + 1.0f > 0.0f) ? BF_GINV : (unsigned short)0;
            gv[e] = v;
        }
        *reinterpret_cast<ushort8v*>(
            &Gpack[((size_t)(jt2 * 128 + it) * 64 + g2 * 16 + qq) * 8]) = gv;
    }
}

// ---------------------------------------------------------------------------
// K2: fused dW GEMM + W update + re-pack + bias grad. 256 blk x 256 thr.
// Block = (kt2, jhalf), SpackB column LDS-staged; 8-deep Gpack prefetch.
// ---------------------------------------------------------------------------
__global__ __launch_bounds__(256) void k_update(
    const unsigned short* __restrict__ Gpack,
    const unsigned short* __restrict__ SpackB,
    float* __restrict__ WT, float* __restrict__ biasp,
    unsigned short* __restrict__ WTpack)
{
    __shared__ unsigned short sB[32768];   // 64 KB: 64 it-tiles of this kt2

    const int bid = blockIdx.x;            // swizzle: mates (kt2,0/1) 8 apart
    const int jhalf = (bid >> 3) & 1;
    const int kt2 = (bid & 7) | ((bid >> 4) << 3);
    const int tid = threadIdx.x, w = tid >> 6, lane = tid & 63;
    const int g = lane >> 4, q = lane & 15;
    const int jt = jhalf * 4 + w;
    const bool bias_tile = (kt2 == 0);

    f32x4 acc = {};
    float bsum = 0.0f;
    const unsigned short* ga = Gpack + (size_t)jt * 128 * 512 + lane * 8;

    for (int half = 0; half < 2; ++half) {
        const unsigned short* src = SpackB + ((size_t)kt2 * 128 + half * 64) * 512;
        __syncthreads();
        #pragma unroll
        for (int u = 0; u < 16; ++u) {
            const int o = (tid + 256 * u) * 8;
            *reinterpret_cast<ushort8v*>(&sB[o]) =
                *reinterpret_cast<const ushort8v*>(&src[o]);
        }
        __syncthreads();

        const unsigned short* gah = ga + (size_t)half * 64 * 512;
        short8v a0[8], a1[8];
        #pragma unroll
        for (int e = 0; e < 8; ++e)
            a0[e] = *reinterpret_cast<const short8v*>(gah + (size_t)e * 512);

        #pragma unroll
        for (int grp = 0; grp < 8; grp += 2) {
            #pragma unroll
            for (int e = 0; e < 8; ++e)
                a1[e] = *reinterpret_cast<const short8v*>(gah + (size_t)((grp + 1) * 8 + e) * 512);
            #pragma unroll
            for (int e = 0; e < 8; ++e) {
                const int it = grp * 8 + e;
                const short8v b = *reinterpret_cast<const short8v*>(&sB[(it * 64 + lane) * 8]);
                acc = MFMA16(a0[e], b, acc);
                if (bias_tile) {
                    #pragma unroll
                    for (int e2 = 0; e2 < 8; ++e2) bsum += bf2f((unsigned short)a0[e][e2]);
                }
            }
            if (grp + 2 < 8) {
                #pragma unroll
                for (int e = 0; e < 8; ++e)
                    a0[e] = *reinterpret_cast<const short8v*>(gah + (size_t)((grp + 2) * 8 + e) * 512);
            }
            #pragma unroll
            for (int e = 0; e < 8; ++e) {
                const int it = (grp + 1) * 8 + e;
                const short8v b = *reinterpret_cast<const short8v*>(&sB[(it * 64 + lane) * 8]);
                acc = MFMA16(a1[e], b, acc);
                if (bias_tile) {
                    #pragma unroll
                    for (int e2 = 0; e2 < 8; ++e2) bsum += bf2f((unsigned short)a1[e][e2]);
                }
            }
        }
    }

    #pragma unroll
    for (int r = 0; r < 4; ++r) {
        const int j = jt * 16 + 4 * g + r;
        const int k = kt2 * 16 + q;
        float wv = WT[(size_t)j * DIM + k];
        wv = wv * SHRINK - LRATE * acc[r];
        WT[(size_t)j * DIM + k] = wv;
        WTpack[((size_t)((k >> 5) * 8 + jt) * 64
                + ((k & 31) >> 3) * 16 + (j & 15)) * 8 + (k & 7)] = f2bf(wv);
    }

    if (bias_tile) {
        bsum += __shfl_xor(bsum, 16);
        bsum += __shfl_xor(bsum, 32);
        if (lane < 16) biasp[jt * 16 + lane] -= LRATE * bsum;
    }
}

// ---------------------------------------------------------------------------
// K3: out = Q @ WT^T + bias. 256 blk x 256 thr; block = 64 rows.
// Per 128-k chunk: stage Q (16 KB bf16, XOR swizzle) AND WT slice (32 KB,
// linear) in LDS, double-buffered; loads for c+1 issued before compute of c.
// ---------------------------------------------------------------------------
__global__ __launch_bounds__(256) void k_query(
    const float* __restrict__ Qf,
    const unsigned short* __restrict__ WTpack,
    const float* __restrict__ bias,
    float* __restrict__ out)
{
    __shared__ __align__(16) unsigned char sQb[2][16384];  // [64 rows][128 k] bf16
    __shared__ __align__(16) unsigned char sWb[2][32768];  // 4 kt x 8 jt x 1KB

    const int tid = threadIdx.x, w = tid >> 6, lane = tid & 63;
    const int g = lane >> 4, q = lane & 15;
    const int row0 = blockIdx.x * 64;
    const float* qbase = Qf + (size_t)row0 * DIM;

    f32x4 acc[8] = {};
    float4   qreg[8];
    ushort8v wreg[8];

    // prologue: load + stage chunk 0
    #pragma unroll
    for (int u = 0; u < 8; ++u) {
        const int s = tid + 256 * u;
        qreg[u] = *reinterpret_cast<const float4*>(
            &qbase[(size_t)(s >> 5) * DIM + ((s & 31) << 2)]);
        wreg[u] = *reinterpret_cast<const ushort8v*>(&WTpack[(size_t)s * 8]);
    }
    #pragma unroll
    for (int u = 0; u < 8; ++u) {
        const int s = tid + 256 * u;
        const int row = s >> 5, c4 = (s & 31) << 2;
        const int byte = (row * 256 + c4 * 2) ^ ((row & 7) << 4);
        ushort4v v;
        v[0] = f2bf(qreg[u].x); v[1] = f2bf(qreg[u].y);
        v[2] = f2bf(qreg[u].z); v[3] = f2bf(qreg[u].w);
        *reinterpret_cast<ushort4v*>(&sQb[0][byte]) = v;
        *reinterpret_cast<ushort8v*>(&sWb[0][s * 16]) = wreg[u];
    }
    __syncthreads();

    const int rbase = (w * 16 + q) * 256;
    const int swz = (q & 7) << 4;

    for (int c = 0; c < 16; ++c) {
        const int cur = c & 1;
        if (c < 15) {   // issue chunk c+1 loads early
            #pragma unroll
            for (int u = 0; u < 8; ++u) {
                const int s = tid + 256 * u;
                qreg[u] = *reinterpret_cast<const float4*>(
                    &qbase[(size_t)(s >> 5) * DIM + (c + 1) * 128 + ((s & 31) << 2)]);
                wreg[u] = *reinterpret_cast<const ushort8v*>(
                    &WTpack[(size_t)(c + 1) * 16384 + (size_t)s * 8]);
            }
        }

        #pragma unroll
        for (int kt_l = 0; kt_l < 4; ++kt_l) {
            const short8v a = *reinterpret_cast<const short8v*>(
                &sQb[cur][(rbase + kt_l * 64 + g * 16) ^ swz]);
            #pragma unroll
            for (int jt = 0; jt < 8; ++jt) {
                const short8v bv = *reinterpret_cast<const short8v*>(
                    &sWb[cur][(kt_l * 8 + jt) * 1024 + lane * 16]);
                acc[jt] = MFMA16(a, bv, acc[jt]);
            }
        }

        if (c < 15) {   // write chunk c+1 into the other buffer
            #pragma unroll
            for (int u = 0; u < 8; ++u) {
                const int s = tid + 256 * u;
                const int row = s >> 5, c4 = (s & 31) << 2;
                const int byte = (row * 256 + c4 * 2) ^ ((row & 7) << 4);
                ushort4v v;
                v[0] = f2bf(qreg[u].x); v[1] = f2bf(qreg[u].y);
                v[2] = f2bf(qreg[u].z); v[3] = f2bf(qreg[u].w);
                *reinterpret_cast<ushort4v*>(&sQb[cur ^ 1][byte]) = v;
                *reinterpret_cast<ushort8v*>(&sWb[cur ^ 1][s * 16]) = wreg[u];
            }
        }
        __syncthreads();
    }

    const int orow0 = row0 + w * 16 + 4 * g;
    #pragma unroll
    for (int jt = 0; jt < 8; ++jt) {
        const float bq = bias[jt * 16 + q];
        #pragma unroll
        for (int r = 0; r < 4; ++r)
            out[(size_t)(orow0 + r) * NC + jt * 16 + q] = acc[jt][r] + bq;
    }
}

// ---------------------------------------------------------------------------
extern "C" void kernel_launch(void* const* d_in, const int* in_sizes, int n_in,
                              void* d_out, int out_size, void* d_ws, size_t ws_size,
                              hipStream_t stream)
{
    const float* S      = (const float*)d_in[0];
    const int*   labels = (const int*)d_in[1];
    const float* Q      = (const float*)d_in[2];
    float* out = (float*)d_out;

    char* ws = (char*)d_ws;
    float*          WT     = (float*)(ws + 0);                 // 1,048,576
    float*          bias   = (float*)(ws + 1048576);           // 512
    unsigned short* WTpack = (unsigned short*)(ws + 1049088);  // 524,288
    unsigned short* Gpack  = (unsigned short*)(ws + 1573376);  // 1,048,576
    unsigned short* SpackA = (unsigned short*)(ws + 2621952);  // 16 MB
    unsigned short* SpackB = (unsigned short*)(ws + 19399168); // 16 MB
    // total: ~36 MB

    hipMemsetAsync(ws, 0, 1573376, stream);   // WT + bias + WTpack

    k_packS<<<dim3(16, 128), 256, 0, stream>>>(S, SpackA, SpackB);

    for (int it = 0; it < MAX_ITER; ++it) {
        k_scores_grad<<<dim3(256), dim3(512), 0, stream>>>(SpackA, WTpack, bias, labels, Gpack);
        k_update<<<dim3(256), dim3(256), 0, stream>>>(Gpack, SpackB, WT, bias, WTpack);
    }
    k_query<<<dim3(256), dim3(256), 0, stream>>>(Q, WTpack, bias, out);
}